// Round 3
// baseline (1015.531 us; speedup 1.0000x reference)
//
#include <hip/hip_runtime.h>
#include <math.h>

#define N_NODES 100000
#define N_EDGES 3200000
#define DIM 16
#define NSZ (N_NODES * DIM)

#define NPB 98          // nodes per bucket
#define NBUCK 1024      // ceil(100000/98)=1021, padded; buckets >=1021 empty
#define LSTR 17         // LDS row stride (DIM+1) to spread banks

// ---- 1) bucket histogram (LDS-aggregated: ~512k global atomics, not 3.2M) ----
__global__ __launch_bounds__(256)
void bucket_hist(const int* __restrict__ col, int* __restrict__ bhist) {
    __shared__ int h[NBUCK];
    for (int j = threadIdx.x; j < NBUCK; j += 256) h[j] = 0;
    __syncthreads();
    for (int e = blockIdx.x * 256 + threadIdx.x; e < N_EDGES;
         e += gridDim.x * 256)
        atomicAdd(&h[col[e] / NPB], 1);
    __syncthreads();
    for (int j = threadIdx.x; j < NBUCK; j += 256)
        if (h[j]) atomicAdd(&bhist[j], h[j]);
}

// ---- 2) exclusive offsets: single-block scan of 1024 bucket counts ----
__global__ __launch_bounds__(NBUCK)
void bucket_scan(const int* __restrict__ bhist, int* __restrict__ off) {
    __shared__ int s[NBUCK];
    int t = threadIdx.x;
    int v = bhist[t];
    s[t] = v;
    __syncthreads();
    for (int d = 1; d < NBUCK; d <<= 1) {
        int u = (t >= d) ? s[t - d] : 0;
        __syncthreads();
        s[t] += u;
        __syncthreads();
    }
    off[t + 1] = s[t];
    if (t == 0) off[0] = 0;
}

// ---- 3) partition: append packed (row|col_local, w) into bucket regions ----
// Appends at the cursor frontier -> dense line fill (frontier = 1024 lines).
__global__ __launch_bounds__(256)
void partition_kernel(const int* __restrict__ row, const int* __restrict__ col,
                      const float* __restrict__ w, const int* __restrict__ off,
                      int* __restrict__ cursor,
                      unsigned long long* __restrict__ packed) {
    int e = blockIdx.x * 256 + threadIdx.x;
    if (e >= N_EDGES) return;
    int c = col[e];
    int b = c / NPB;                       // const-div -> magic multiply
    int pos = off[b] + atomicAdd(&cursor[b], 1);
    unsigned hi = ((unsigned)row[e] << 7) | (unsigned)(c - b * NPB);
    packed[pos] = ((unsigned long long)hi << 32) | __float_as_uint(w[e]);
}

// ---- 4) per-bucket aggregation + full epilogue, LDS accumulator ----
__global__ __launch_bounds__(256)
void bucket_aggregate(const float* __restrict__ state,
                      const int* __restrict__ off,
                      const unsigned long long* __restrict__ packed,
                      float* __restrict__ out) {
    __shared__ float acc[NPB * LSTR];
    __shared__ float xc[NPB * LSTR];
    int b = blockIdx.x;
    int n0 = b * NPB;
    int cnt = N_NODES - n0;
    if (cnt <= 0) return;                  // buckets 1021..1023
    if (cnt > NPB) cnt = NPB;
    int t = threadIdx.x;
    for (int i = t; i < cnt * DIM; i += 256) {
        int cl = i >> 4, d = i & 15;
        xc[cl * LSTR + d] = state[n0 * DIM + i];   // coalesced read
    }
    for (int i = t; i < NPB * LSTR; i += 256) acc[i] = 0.f;
    __syncthreads();

    int beg = off[b], end = off[b + 1];
    for (int i = beg + t; i < end; i += 256) {
        unsigned long long p = packed[i];          // coalesced 8B
        float we = __uint_as_float((unsigned)(p & 0xffffffffull));
        unsigned hi = (unsigned)(p >> 32);
        int cl = hi & 127;
        int r = (int)(hi >> 7);
        const float4* sp = (const float4*)(state + r * DIM);
        float4 x0 = sp[0], x1 = sp[1], x2 = sp[2], x3 = sp[3];
        float xr[16] = {x0.x, x0.y, x0.z, x0.w, x1.x, x1.y, x1.z, x1.w,
                        x2.x, x2.y, x2.z, x2.w, x3.x, x3.y, x3.z, x3.w};
        float* arow = &acc[cl * LSTR];
        const float* crow = &xc[cl * LSTR];
        #pragma unroll
        for (int d = 0; d < 16; ++d) {
            float s = __sinf(xr[d] - crow[d]) * we;
            atomicAdd(&arow[d], s);                // ds_add_f32
        }
    }
    __syncthreads();

    // epilogue: this block owns nodes [n0, n0+cnt) exclusively
    for (int i = t; i < cnt * DIM; i += 256) {
        int cl = i >> 4, d = i & 15;
        float a = acc[cl * LSTR + d];
        float x = xc[cl * LSTR + d];
        float th = tanhf(a);
        int g = n0 * DIM + i;                      // coalesced writes
        out[0 * NSZ + g] = th - x;   // self_diff + interact_diff
        out[1 * NSZ + g] = x;        // state_input
        out[2 * NSZ + g] = -x;       // self_diff
        out[3 * NSZ + g] = a;        // aggregated_sum
        out[4 * NSZ + g] = th;       // interact_diff
    }
}

// ---- fallback (tiny ws): round-1 atomic path ----
__global__ __launch_bounds__(256)
void edge_kernel(const float* __restrict__ state, const int* __restrict__ row,
                 const int* __restrict__ col, const float* __restrict__ w,
                 float* __restrict__ agg) {
    int idx = blockIdx.x * blockDim.x + threadIdx.x;
    if (idx >= N_EDGES * 4) return;
    int e = idx >> 2, q = idx & 3;
    int r = row[e], c = col[e];
    float we = w[e];
    const float4 xr = ((const float4*)state)[r * 4 + q];
    const float4 xcv = ((const float4*)state)[c * 4 + q];
    float* dst = agg + c * DIM + q * 4;
    atomicAdd(dst + 0, sinf(xr.x - xcv.x) * we);
    atomicAdd(dst + 1, sinf(xr.y - xcv.y) * we);
    atomicAdd(dst + 2, sinf(xr.z - xcv.z) * we);
    atomicAdd(dst + 3, sinf(xr.w - xcv.w) * we);
}

__global__ __launch_bounds__(256)
void node_kernel(const float* __restrict__ state, const float* __restrict__ agg,
                 float* __restrict__ out) {
    int idx = blockIdx.x * blockDim.x + threadIdx.x;
    if (idx >= N_NODES * 4) return;
    float4 x = ((const float4*)state)[idx];
    float4 a = ((const float4*)agg)[idx];
    float4 tv = make_float4(tanhf(a.x), tanhf(a.y), tanhf(a.z), tanhf(a.w));
    ((float4*)(out + 0 * NSZ))[idx] = make_float4(tv.x - x.x, tv.y - x.y,
                                                  tv.z - x.z, tv.w - x.w);
    ((float4*)(out + 1 * NSZ))[idx] = x;
    ((float4*)(out + 2 * NSZ))[idx] = make_float4(-x.x, -x.y, -x.z, -x.w);
    ((float4*)(out + 4 * NSZ))[idx] = tv;
}

extern "C" void kernel_launch(void* const* d_in, const int* in_sizes, int n_in,
                              void* d_out, int out_size, void* d_ws, size_t ws_size,
                              hipStream_t stream) {
    const float* state = (const float*)d_in[0];
    const int*   row   = (const int*)d_in[1];
    const int*   col   = (const int*)d_in[2];
    const float* w     = (const float*)d_in[3];
    float* out = (float*)d_out;

    size_t head_ints = (size_t)NBUCK + NBUCK + (NBUCK + 1);
    size_t packed_off = (head_ints * 4 + 7) & ~(size_t)7;
    size_t needed = packed_off + (size_t)N_EDGES * 8;

    if (ws_size >= needed) {
        int* bhist  = (int*)d_ws;            // NBUCK
        int* cursor = bhist + NBUCK;         // NBUCK
        int* off    = cursor + NBUCK;        // NBUCK+1
        unsigned long long* packed =
            (unsigned long long*)((char*)d_ws + packed_off);

        hipMemsetAsync(d_ws, 0, (size_t)2 * NBUCK * sizeof(int), stream);
        bucket_hist<<<512, 256, 0, stream>>>(col, bhist);
        bucket_scan<<<1, NBUCK, 0, stream>>>(bhist, off);
        partition_kernel<<<(N_EDGES + 255) / 256, 256, 0, stream>>>(
            row, col, w, off, cursor, packed);
        bucket_aggregate<<<NBUCK, 256, 0, stream>>>(state, off, packed, out);
    } else {
        float* agg = out + 3 * NSZ;
        hipMemsetAsync(agg, 0, NSZ * sizeof(float), stream);
        edge_kernel<<<(N_EDGES * 4 + 255) / 256, 256, 0, stream>>>(
            state, row, col, w, agg);
        node_kernel<<<(N_NODES * 4 + 255) / 256, 256, 0, stream>>>(
            state, agg, out);
    }
}

// Round 4
// 471.183 us; speedup vs baseline: 2.1553x; 2.1553x over previous
//
#include <hip/hip_runtime.h>
#include <math.h>

#define N_NODES 100000
#define N_EDGES 3200000
#define DIM 16
#define NSZ (N_NODES * DIM)

#define NPB 98          // nodes per bucket
#define NBUCK 1024      // ceil(100000/98)=1021 used; 1021..1023 empty
#define LSTR 17         // LDS row stride (DIM+1): odd -> spreads 32 banks
#define EPB 8192        // edges per partition block
#define PBLOCKS ((N_EDGES + EPB - 1) / EPB)   // 391

// ---- 1) bucket histogram (LDS-aggregated) ----
__global__ __launch_bounds__(256)
void bucket_hist(const int* __restrict__ col, int* __restrict__ bhist) {
    __shared__ int h[NBUCK];
    for (int j = threadIdx.x; j < NBUCK; j += 256) h[j] = 0;
    __syncthreads();
    for (int e = blockIdx.x * 256 + threadIdx.x; e < N_EDGES;
         e += gridDim.x * 256)
        atomicAdd(&h[col[e] / NPB], 1);
    __syncthreads();
    for (int j = threadIdx.x; j < NBUCK; j += 256)
        if (h[j]) atomicAdd(&bhist[j], h[j]);
}

// ---- 2) exclusive offsets over 1024 buckets (single block) ----
__global__ __launch_bounds__(NBUCK)
void bucket_scan(const int* __restrict__ bhist, int* __restrict__ off) {
    __shared__ int s[NBUCK];
    int t = threadIdx.x;
    int v = bhist[t];
    s[t] = v;
    __syncthreads();
    for (int d = 1; d < NBUCK; d <<= 1) {
        int u = (t >= d) ? s[t - d] : 0;
        __syncthreads();
        s[t] += u;
        __syncthreads();
    }
    off[t + 1] = s[t];
    if (t == 0) off[0] = 0;
}

// ---- 3) partition with per-(block,bucket) reservation ----
// Phase 1: LDS histogram of this block's 8192 edges.
// Phase 2: ONE global atomicAdd per touched bucket (<=1024/block) -> base.
// Phase 3: re-stream edges, rank via LDS cursor, write packed 8B into runs.
__global__ __launch_bounds__(256)
void partition_block(const int* __restrict__ row, const int* __restrict__ col,
                     const float* __restrict__ w, const int* __restrict__ off,
                     int* __restrict__ cursor,
                     unsigned long long* __restrict__ packed) {
    __shared__ int hcnt[NBUCK];   // 4KB: per-block bucket counts, then cursors
    __shared__ int base[NBUCK];   // 4KB: reserved global base per bucket
    int t = threadIdx.x;
    int e0 = blockIdx.x * EPB;
    int e1 = e0 + EPB; if (e1 > N_EDGES) e1 = N_EDGES;

    for (int j = t; j < NBUCK; j += 256) hcnt[j] = 0;
    __syncthreads();
    for (int e = e0 + t; e < e1; e += 256)
        atomicAdd(&hcnt[col[e] / NPB], 1);
    __syncthreads();
    for (int j = t; j < NBUCK; j += 256) {
        int c = hcnt[j];
        base[j] = c ? (off[j] + atomicAdd(&cursor[j], c)) : 0;
        hcnt[j] = 0;               // reuse as intra-block rank cursor
    }
    __syncthreads();
    for (int e = e0 + t; e < e1; e += 256) {
        int c = col[e];
        int b = c / NPB;
        int rank = atomicAdd(&hcnt[b], 1);            // LDS, fast
        unsigned hi = ((unsigned)row[e] << 7) | (unsigned)(c - b * NPB);
        packed[base[b] + rank] =
            ((unsigned long long)hi << 32) | __float_as_uint(w[e]);
    }
}

// ---- 4) per-bucket aggregation + fused epilogue ----
__device__ __forceinline__ void decode_edge(unsigned long long p, int& cl,
                                            int& r, float& we) {
    we = __uint_as_float((unsigned)p);
    unsigned hi = (unsigned)(p >> 32);
    cl = (int)(hi & 127u);
    r = (int)(hi >> 7);
}

__device__ __forceinline__ void accum_edge(int cl, float we, float4 x0,
                                           float4 x1, float4 x2, float4 x3,
                                           const float* __restrict__ xc,
                                           float* __restrict__ ac) {
    const float* crow = xc + cl * LSTR;
    float* arow = ac + cl * LSTR;
    float xr[16] = {x0.x, x0.y, x0.z, x0.w, x1.x, x1.y, x1.z, x1.w,
                    x2.x, x2.y, x2.z, x2.w, x3.x, x3.y, x3.z, x3.w};
    #pragma unroll
    for (int d = 0; d < 16; ++d)
        atomicAdd(&arow[d], __sinf(xr[d] - crow[d]) * we);   // ds_add_f32
}

__global__ __launch_bounds__(256)
void bucket_aggregate(const float* __restrict__ state,
                      const int* __restrict__ off,
                      const unsigned long long* __restrict__ packed,
                      float* __restrict__ out) {
    __shared__ float xc[NPB * LSTR];   // 6.7KB
    __shared__ float ac[NPB * LSTR];   // 6.7KB
    int b = blockIdx.x;
    int n0 = b * NPB;
    int cnt = N_NODES - n0;
    if (cnt <= 0) return;
    if (cnt > NPB) cnt = NPB;
    int t = threadIdx.x;
    for (int i = t; i < cnt * DIM; i += 256) {
        int cl = i >> 4, d = i & 15;
        xc[cl * LSTR + d] = state[n0 * DIM + i];
    }
    for (int i = t; i < NPB * LSTR; i += 256) ac[i] = 0.f;
    __syncthreads();

    int beg = off[b], end = off[b + 1];
    int i = beg + t;
    // unroll-2: two independent 64B gathers in flight per iteration
    for (; i + 256 < end; i += 512) {
        unsigned long long p0 = packed[i];
        unsigned long long p1 = packed[i + 256];
        int cl0, r0, cl1, r1; float w0, w1;
        decode_edge(p0, cl0, r0, w0);
        decode_edge(p1, cl1, r1, w1);
        const float4* s0 = (const float4*)(state + r0 * DIM);
        const float4* s1 = (const float4*)(state + r1 * DIM);
        float4 a0 = s0[0], a1 = s0[1], a2 = s0[2], a3 = s0[3];
        float4 b0 = s1[0], b1 = s1[1], b2 = s1[2], b3 = s1[3];
        accum_edge(cl0, w0, a0, a1, a2, a3, xc, ac);
        accum_edge(cl1, w1, b0, b1, b2, b3, xc, ac);
    }
    if (i < end) {
        unsigned long long p0 = packed[i];
        int cl0, r0; float w0;
        decode_edge(p0, cl0, r0, w0);
        const float4* s0 = (const float4*)(state + r0 * DIM);
        accum_edge(cl0, w0, s0[0], s0[1], s0[2], s0[3], xc, ac);
    }
    __syncthreads();

    for (int i2 = t; i2 < cnt * DIM; i2 += 256) {
        int cl = i2 >> 4, d = i2 & 15;
        float a = ac[cl * LSTR + d];
        float x = xc[cl * LSTR + d];
        float th = tanhf(a);
        int g = n0 * DIM + i2;
        out[0 * NSZ + g] = th - x;
        out[1 * NSZ + g] = x;
        out[2 * NSZ + g] = -x;
        out[3 * NSZ + g] = a;
        out[4 * NSZ + g] = th;
    }
}

// ---- fallback (tiny ws): round-1 atomic path ----
__global__ __launch_bounds__(256)
void edge_kernel(const float* __restrict__ state, const int* __restrict__ row,
                 const int* __restrict__ col, const float* __restrict__ w,
                 float* __restrict__ agg) {
    int idx = blockIdx.x * blockDim.x + threadIdx.x;
    if (idx >= N_EDGES * 4) return;
    int e = idx >> 2, q = idx & 3;
    int r = row[e], c = col[e];
    float we = w[e];
    const float4 xr = ((const float4*)state)[r * 4 + q];
    const float4 xcv = ((const float4*)state)[c * 4 + q];
    float* dst = agg + c * DIM + q * 4;
    atomicAdd(dst + 0, sinf(xr.x - xcv.x) * we);
    atomicAdd(dst + 1, sinf(xr.y - xcv.y) * we);
    atomicAdd(dst + 2, sinf(xr.z - xcv.z) * we);
    atomicAdd(dst + 3, sinf(xr.w - xcv.w) * we);
}

__global__ __launch_bounds__(256)
void node_kernel(const float* __restrict__ state, const float* __restrict__ agg,
                 float* __restrict__ out) {
    int idx = blockIdx.x * blockDim.x + threadIdx.x;
    if (idx >= N_NODES * 4) return;
    float4 x = ((const float4*)state)[idx];
    float4 a = ((const float4*)agg)[idx];
    float4 tv = make_float4(tanhf(a.x), tanhf(a.y), tanhf(a.z), tanhf(a.w));
    ((float4*)(out + 0 * NSZ))[idx] = make_float4(tv.x - x.x, tv.y - x.y,
                                                  tv.z - x.z, tv.w - x.w);
    ((float4*)(out + 1 * NSZ))[idx] = x;
    ((float4*)(out + 2 * NSZ))[idx] = make_float4(-x.x, -x.y, -x.z, -x.w);
    ((float4*)(out + 4 * NSZ))[idx] = tv;
}

extern "C" void kernel_launch(void* const* d_in, const int* in_sizes, int n_in,
                              void* d_out, int out_size, void* d_ws, size_t ws_size,
                              hipStream_t stream) {
    const float* state = (const float*)d_in[0];
    const int*   row   = (const int*)d_in[1];
    const int*   col   = (const int*)d_in[2];
    const float* w     = (const float*)d_in[3];
    float* out = (float*)d_out;

    size_t head_ints = (size_t)NBUCK + NBUCK + (NBUCK + 1);
    size_t packed_off = (head_ints * 4 + 7) & ~(size_t)7;
    size_t needed = packed_off + (size_t)N_EDGES * 8;

    if (ws_size >= needed) {
        int* bhist  = (int*)d_ws;            // NBUCK
        int* cursor = bhist + NBUCK;         // NBUCK
        int* off    = cursor + NBUCK;        // NBUCK+1
        unsigned long long* packed =
            (unsigned long long*)((char*)d_ws + packed_off);

        hipMemsetAsync(d_ws, 0, (size_t)2 * NBUCK * sizeof(int), stream);
        bucket_hist<<<512, 256, 0, stream>>>(col, bhist);
        bucket_scan<<<1, NBUCK, 0, stream>>>(bhist, off);
        partition_block<<<PBLOCKS, 256, 0, stream>>>(row, col, w, off,
                                                     cursor, packed);
        bucket_aggregate<<<NBUCK, 256, 0, stream>>>(state, off, packed, out);
    } else {
        float* agg = out + 3 * NSZ;
        hipMemsetAsync(agg, 0, NSZ * sizeof(float), stream);
        edge_kernel<<<(N_EDGES * 4 + 255) / 256, 256, 0, stream>>>(
            state, row, col, w, agg);
        node_kernel<<<(N_NODES * 4 + 255) / 256, 256, 0, stream>>>(
            state, agg, out);
    }
}